// Round 4
// baseline (716.800 us; speedup 1.0000x reference)
//
#include <hip/hip_runtime.h>
#include <hip/hip_cooperative_groups.h>
#include <math.h>

namespace cg = cooperative_groups;

#define NFIELD 3
#define FEAT 256   // D == O == 256

typedef __attribute__((ext_vector_type(8))) short frag_ab;   // 8 bf16 (4 VGPRs)
typedef __attribute__((ext_vector_type(4))) float frag_cd;   // 4 fp32 acc

__device__ __forceinline__ unsigned short f2bf(float f) {
    unsigned int u = __float_as_uint(f);
    u = (u + 0x7fffu + ((u >> 16) & 1u)) >> 16;   // RNE
    return (unsigned short)u;
}
__device__ __forceinline__ float bf2f(unsigned short b) {
    return __uint_as_float(((unsigned int)b) << 16);
}

// ---------------- fused prep (cooperative): ----------------
// phase0: zero dnrm/count + cvt_w + cvt_x   (independent work)
// phase1: degree count + weighted-degree atomics
// phase2: exclusive scan -> rowptr/cursor + dnrm = rsqrt(deg)   (block 0)
// phase3: fill packed edge records (src, norm)
// R4 theory: R0-R3 showed a constant ~280us non-gather residual spread over
// 6 small serialized dispatches; fuse them into one cooperative launch.
__global__ __launch_bounds__(256) void k_prep(
        int2* __restrict__ erec, float* __restrict__ dnrm, int* __restrict__ count,
        int* __restrict__ rowptr, int* __restrict__ cursor,
        const int* __restrict__ ei, const float* __restrict__ ew,
        const float* __restrict__ x, unsigned short* __restrict__ xb,
        const float* __restrict__ Wg, const float* __restrict__ Wr,
        const float* __restrict__ Wh,
        unsigned short* __restrict__ wgT, unsigned short* __restrict__ wrT,
        unsigned short* __restrict__ whT,
        int n, int E, int cnt4) {
    cg::grid_group grid = cg::this_grid();
    __shared__ int part[256];

    int t    = threadIdx.x;
    int gtid = blockIdx.x * blockDim.x + t;
    int gsz  = gridDim.x * blockDim.x;

    // ---- phase 0 ----
    for (int i = gtid; i < n; i += gsz) { dnrm[i] = 2.0f; count[i] = 0; }
    for (int i = gtid; i < NFIELD * FEAT * FEAT; i += gsz) {
        int f = i >> 16;
        int r = i & 0xffff;
        int d = r >> 8;          // k index in source row-major [d][o]
        int o = r & 255;
        int tdst = (f << 16) | (o << 8) | d;
        wgT[tdst] = f2bf(Wg[i]);
        whT[tdst] = f2bf(Wh[i]);
        wrT[i]    = f2bf(Wr[i]);   // already [o][k]
    }
    for (int i = gtid; i < cnt4; i += gsz) {
        float4 v = *((const float4*)x + i);
        ushort4 o;
        o.x = f2bf(v.x); o.y = f2bf(v.y); o.z = f2bf(v.z); o.w = f2bf(v.w);
        *((ushort4*)xb + i) = o;
    }
    grid.sync();

    // ---- phase 1: count ----
    const int* col = ei + E;
    for (int e = gtid; e < E; e += gsz) {
        int c = col[e];
        atomicAdd(&count[c], 1);
        atomicAdd(&dnrm[c], ew[e]);
    }
    grid.sync();

    // ---- phase 2: scan (block 0 only) ----
    if (blockIdx.x == 0) {
        int ch = (n + 255) / 256;
        int c0 = t * ch, c1 = min(n, c0 + ch);
        int s = 0;
        for (int c = c0; c < c1; ++c) s += count[c];
        part[t] = s;
        __syncthreads();
        for (int off = 1; off < 256; off <<= 1) {
            int v = (t >= off) ? part[t - off] : 0;
            __syncthreads();
            part[t] += v;
            __syncthreads();
        }
        int base = part[t] - s;   // exclusive prefix
        for (int c = c0; c < c1; ++c) {
            rowptr[c] = base; cursor[c] = base; base += count[c];
            float d = dnrm[c];
            dnrm[c] = d > 0.0f ? rsqrtf(d) : 0.0f;
        }
        if (t == 0) rowptr[n] = E;
    }
    grid.sync();

    // ---- phase 3: fill ----
    for (int e = gtid; e < E; e += gsz) {
        int r = ei[e];
        int c = col[e];
        float nm = dnrm[r] * ew[e] * dnrm[c];
        int p = atomicAdd(&cursor[c], 1);
        erec[p] = make_int2(r, __float_as_int(nm));
    }
}

// ---------------- standalone prep kernels (fallback path only) ----------------

__global__ void k_zero(float* dnrm, int* count, int n) {
    int i = blockIdx.x * blockDim.x + threadIdx.x;
    if (i < n) { dnrm[i] = 2.0f; count[i] = 0; }
}

__global__ void k_count(const int* __restrict__ col, const float* __restrict__ w,
                        float* dnrm, int* count, int E) {
    int e = blockIdx.x * blockDim.x + threadIdx.x;
    if (e < E) {
        int c = col[e];
        atomicAdd(&count[c], 1);
        atomicAdd(&dnrm[c], w[e]);
    }
}

#define SCAN_T 1024
__global__ __launch_bounds__(SCAN_T) void k_scan(const int* __restrict__ count,
        float* dnrm, int* rowptr, int* cursor, int n, int E) {
    __shared__ int part[SCAN_T];
    int t = threadIdx.x;
    int ch = (n + SCAN_T - 1) / SCAN_T;
    int c0 = t * ch, c1 = min(n, c0 + ch);
    int s = 0;
    for (int c = c0; c < c1; ++c) s += count[c];
    part[t] = s;
    __syncthreads();
    for (int off = 1; off < SCAN_T; off <<= 1) {
        int v = (t >= off) ? part[t - off] : 0;
        __syncthreads();
        part[t] += v;
        __syncthreads();
    }
    int base = part[t] - s;
    for (int c = c0; c < c1; ++c) {
        rowptr[c] = base; cursor[c] = base; base += count[c];
        float d = dnrm[c];
        dnrm[c] = d > 0.0f ? rsqrtf(d) : 0.0f;
    }
    if (t == 0) rowptr[n] = E;
}

__global__ void k_fill(const int* __restrict__ ei, const float* __restrict__ ew,
                       const float* __restrict__ dnrm, int* cursor,
                       int2* __restrict__ erec, int E) {
    int e = blockIdx.x * blockDim.x + threadIdx.x;
    if (e < E) {
        int r = ei[e];
        int c = ei[E + e];
        float nm = dnrm[r] * ew[e] * dnrm[c];
        int p = atomicAdd(&cursor[c], 1);
        erec[p] = make_int2(r, __float_as_int(nm));
    }
}

__global__ void k_cvt_x(const float* __restrict__ src, unsigned short* __restrict__ dst,
                        int count4) {
    int i = blockIdx.x * blockDim.x + threadIdx.x;
    if (i >= count4) return;
    float4 v = *((const float4*)src + i);
    ushort4 o;
    o.x = f2bf(v.x); o.y = f2bf(v.y); o.z = f2bf(v.z); o.w = f2bf(v.w);
    *((ushort4*)dst + i) = o;
}

__global__ void k_cvt_w(const float* __restrict__ Wg, const float* __restrict__ Wr,
                        const float* __restrict__ Wh,
                        unsigned short* __restrict__ wgT, unsigned short* __restrict__ wrT,
                        unsigned short* __restrict__ whT) {
    int i = blockIdx.x * blockDim.x + threadIdx.x;
    if (i >= NFIELD * FEAT * FEAT) return;
    int f = i >> 16;
    int r = i & 0xffff;
    int d = r >> 8;
    int o = r & 255;
    int tdst = (f << 16) | (o << 8) | d;
    wgT[tdst] = f2bf(Wg[i]);
    whT[tdst] = f2bf(Wh[i]);
    wrT[i]    = f2bf(Wr[i]);
}

// ---------------- gather (R1 form — best measured: 71us, 3.7 TB/s) ----------------
// xa[fl,c,:] = 2*dinv_c^2 * x[fl,c,:] + sum_e nrm_e * x[fl,src_e,:]
// one wave per destination node; 4-edge unroll -> 12 independent row loads
// in flight; 16B-aligned int4 fetch of record pairs (peel odd beg).
__global__ void k_gather(const int2* __restrict__ erec,
                         const float* __restrict__ dnrm, const int* __restrict__ rowptr,
                         const unsigned short* __restrict__ xb,
                         unsigned short* __restrict__ xab,
                         int n, int fl_count) {
    int wid  = blockIdx.x * (blockDim.x >> 6) + (threadIdx.x >> 6);
    int lane = threadIdx.x & 63;
    if (wid >= n) return;
    int c = wid;
    int beg = rowptr[c], end = rowptr[c + 1];
    float dc = dnrm[c];
    float s  = 2.0f * dc * dc;
    const size_t nf = (size_t)n * FEAT;

    float acc[NFIELD][4];
    #pragma unroll
    for (int fl = 0; fl < NFIELD; ++fl) {
        if (fl >= fl_count) break;
        ushort4 v = ((const ushort4*)(xb + fl * nf + (size_t)c * FEAT))[lane];
        acc[fl][0] = s * bf2f(v.x); acc[fl][1] = s * bf2f(v.y);
        acc[fl][2] = s * bf2f(v.z); acc[fl][3] = s * bf2f(v.w);
    }

    int i = beg;
    if (fl_count == NFIELD) {
        if ((i & 1) && i < end) {
            int2 ra = erec[i];
            const unsigned short* pa = xb + (size_t)ra.x * FEAT;
            float na = __int_as_float(ra.y);
            ushort4 va0 = ((const ushort4*)pa)[lane];
            ushort4 va1 = ((const ushort4*)(pa + nf))[lane];
            ushort4 va2 = ((const ushort4*)(pa + 2 * nf))[lane];
            acc[0][0] += na * bf2f(va0.x); acc[0][1] += na * bf2f(va0.y);
            acc[0][2] += na * bf2f(va0.z); acc[0][3] += na * bf2f(va0.w);
            acc[1][0] += na * bf2f(va1.x); acc[1][1] += na * bf2f(va1.y);
            acc[1][2] += na * bf2f(va1.z); acc[1][3] += na * bf2f(va1.w);
            acc[2][0] += na * bf2f(va2.x); acc[2][1] += na * bf2f(va2.y);
            acc[2][2] += na * bf2f(va2.z); acc[2][3] += na * bf2f(va2.w);
            ++i;
        }
        for (; i + 3 < end; i += 4) {
            int4 qa = *(const int4*)&erec[i];
            int4 qb = *(const int4*)&erec[i + 2];
            const unsigned short* p0 = xb + (size_t)qa.x * FEAT;
            const unsigned short* p1 = xb + (size_t)qa.z * FEAT;
            const unsigned short* p2 = xb + (size_t)qb.x * FEAT;
            const unsigned short* p3 = xb + (size_t)qb.z * FEAT;
            float n0 = __int_as_float(qa.y);
            float n1 = __int_as_float(qa.w);
            float n2 = __int_as_float(qb.y);
            float n3 = __int_as_float(qb.w);
            ushort4 v[4][NFIELD];
            v[0][0] = ((const ushort4*)p0)[lane];
            v[1][0] = ((const ushort4*)p1)[lane];
            v[2][0] = ((const ushort4*)p2)[lane];
            v[3][0] = ((const ushort4*)p3)[lane];
            v[0][1] = ((const ushort4*)(p0 + nf))[lane];
            v[1][1] = ((const ushort4*)(p1 + nf))[lane];
            v[2][1] = ((const ushort4*)(p2 + nf))[lane];
            v[3][1] = ((const ushort4*)(p3 + nf))[lane];
            v[0][2] = ((const ushort4*)(p0 + 2 * nf))[lane];
            v[1][2] = ((const ushort4*)(p1 + 2 * nf))[lane];
            v[2][2] = ((const ushort4*)(p2 + 2 * nf))[lane];
            v[3][2] = ((const ushort4*)(p3 + 2 * nf))[lane];
            #pragma unroll
            for (int fl = 0; fl < NFIELD; ++fl) {
                acc[fl][0] += n0 * bf2f(v[0][fl].x) + n1 * bf2f(v[1][fl].x)
                            + n2 * bf2f(v[2][fl].x) + n3 * bf2f(v[3][fl].x);
                acc[fl][1] += n0 * bf2f(v[0][fl].y) + n1 * bf2f(v[1][fl].y)
                            + n2 * bf2f(v[2][fl].y) + n3 * bf2f(v[3][fl].y);
                acc[fl][2] += n0 * bf2f(v[0][fl].z) + n1 * bf2f(v[1][fl].z)
                            + n2 * bf2f(v[2][fl].z) + n3 * bf2f(v[3][fl].z);
                acc[fl][3] += n0 * bf2f(v[0][fl].w) + n1 * bf2f(v[1][fl].w)
                            + n2 * bf2f(v[2][fl].w) + n3 * bf2f(v[3][fl].w);
            }
        }
        for (; i + 1 < end; i += 2) {
            int4 qa = *(const int4*)&erec[i];
            const unsigned short* pa = xb + (size_t)qa.x * FEAT;
            const unsigned short* pb = xb + (size_t)qa.z * FEAT;
            float na = __int_as_float(qa.y);
            float nb = __int_as_float(qa.w);
            ushort4 va0 = ((const ushort4*)pa)[lane];
            ushort4 vb0 = ((const ushort4*)pb)[lane];
            ushort4 va1 = ((const ushort4*)(pa + nf))[lane];
            ushort4 vb1 = ((const ushort4*)(pb + nf))[lane];
            ushort4 va2 = ((const ushort4*)(pa + 2 * nf))[lane];
            ushort4 vb2 = ((const ushort4*)(pb + 2 * nf))[lane];
            acc[0][0] += na * bf2f(va0.x) + nb * bf2f(vb0.x);
            acc[0][1] += na * bf2f(va0.y) + nb * bf2f(vb0.y);
            acc[0][2] += na * bf2f(va0.z) + nb * bf2f(vb0.z);
            acc[0][3] += na * bf2f(va0.w) + nb * bf2f(vb0.w);
            acc[1][0] += na * bf2f(va1.x) + nb * bf2f(vb1.x);
            acc[1][1] += na * bf2f(va1.y) + nb * bf2f(vb1.y);
            acc[1][2] += na * bf2f(va1.z) + nb * bf2f(vb1.z);
            acc[1][3] += na * bf2f(va1.w) + nb * bf2f(vb1.w);
            acc[2][0] += na * bf2f(va2.x) + nb * bf2f(vb2.x);
            acc[2][1] += na * bf2f(va2.y) + nb * bf2f(vb2.y);
            acc[2][2] += na * bf2f(va2.z) + nb * bf2f(vb2.z);
            acc[2][3] += na * bf2f(va2.w) + nb * bf2f(vb2.w);
        }
        for (; i < end; ++i) {
            int2 ra = erec[i];
            const unsigned short* pa = xb + (size_t)ra.x * FEAT;
            float na = __int_as_float(ra.y);
            ushort4 va0 = ((const ushort4*)pa)[lane];
            ushort4 va1 = ((const ushort4*)(pa + nf))[lane];
            ushort4 va2 = ((const ushort4*)(pa + 2 * nf))[lane];
            acc[0][0] += na * bf2f(va0.x); acc[0][1] += na * bf2f(va0.y);
            acc[0][2] += na * bf2f(va0.z); acc[0][3] += na * bf2f(va0.w);
            acc[1][0] += na * bf2f(va1.x); acc[1][1] += na * bf2f(va1.y);
            acc[1][2] += na * bf2f(va1.z); acc[1][3] += na * bf2f(va1.w);
            acc[2][0] += na * bf2f(va2.x); acc[2][1] += na * bf2f(va2.y);
            acc[2][2] += na * bf2f(va2.z); acc[2][3] += na * bf2f(va2.w);
        }
    } else {
        for (; i < end; ++i) {
            int2 ra = erec[i];
            const unsigned short* pa = xb + (size_t)ra.x * FEAT;
            float na = __int_as_float(ra.y);
            ushort4 va0 = ((const ushort4*)pa)[lane];
            acc[0][0] += na * bf2f(va0.x); acc[0][1] += na * bf2f(va0.y);
            acc[0][2] += na * bf2f(va0.z); acc[0][3] += na * bf2f(va0.w);
        }
    }

    #pragma unroll
    for (int fl = 0; fl < NFIELD; ++fl) {
        if (fl >= fl_count) break;
        ushort4 o;
        o.x = f2bf(acc[fl][0]); o.y = f2bf(acc[fl][1]);
        o.z = f2bf(acc[fl][2]); o.w = f2bf(acc[fl][3]);
        ((ushort4*)(xab + fl * nf + (size_t)c * FEAT))[lane] = o;
    }
}

// ---------------- MFMA GEMM + highway + leaky_relu ----------------
#define BM 64
#define BN 128
#define BK 32

__device__ __forceinline__ int swz(int row, int quad) {
    return (quad ^ ((row >> 1) & 3)) * 8;
}

__global__ __launch_bounds__(256) void k_gemm_mfma(
    const unsigned short* __restrict__ xb, const unsigned short* __restrict__ xab,
    const unsigned short* __restrict__ wgT, const unsigned short* __restrict__ wrT,
    const unsigned short* __restrict__ whT,
    float* __restrict__ out, int n, int f_base) {

    __shared__ unsigned short As_x[BM][BK];
    __shared__ unsigned short As_a[BM][BK];
    __shared__ unsigned short Bs[3][BN][BK];   // g, r, h

    int fl = blockIdx.z;
    int f  = f_base + fl;
    int m0 = blockIdx.x * BM;
    int o0 = blockIdx.y * BN;
    int t  = threadIdx.x;

    const unsigned short* xf  = xb  + (size_t)fl * n * FEAT;
    const unsigned short* xaf = xab + (size_t)fl * n * FEAT;
    const unsigned short* wsrc0 = wgT + ((size_t)f << 16);
    const unsigned short* wsrc1 = wrT + ((size_t)f << 16);
    const unsigned short* wsrc2 = whT + ((size_t)f << 16);

    int w    = t >> 6;
    int lane = t & 63;
    int lrow = lane & 15;
    int quad = lane >> 4;
    int wn   = w * 32;

    frag_cd acc[3][4][2];
    #pragma unroll
    for (int s = 0; s < 3; ++s)
        #pragma unroll
        for (int mi = 0; mi < 4; ++mi)
            #pragma unroll
            for (int ni = 0; ni < 2; ++ni)
                acc[s][mi][ni] = (frag_cd){0.f, 0.f, 0.f, 0.f};

    int arow = t >> 2;
    int aq   = (t & 3) * 8;
    int adst = swz(arow, t & 3);
    int am   = min(m0 + arow, n - 1);

    for (int k0 = 0; k0 < FEAT; k0 += BK) {
        *(uint4*)&As_x[arow][adst] = *(const uint4*)(xf  + (size_t)am * FEAT + k0 + aq);
        *(uint4*)&As_a[arow][adst] = *(const uint4*)(xaf + (size_t)am * FEAT + k0 + aq);
        #pragma unroll
        for (int s = 0; s < 6; ++s) {
            int buf = s >> 1;
            int row = (s & 1) * 64 + (t >> 2);
            const unsigned short* wsrc = (buf == 0) ? wsrc0 : (buf == 1) ? wsrc1 : wsrc2;
            *(uint4*)&Bs[buf][row][swz(row, t & 3)] =
                *(const uint4*)(wsrc + ((o0 + row) << 8) + k0 + aq);
        }
        __syncthreads();

        frag_ab ax[4], aa[4], bg[2], br[2], bh[2];
        #pragma unroll
        for (int mi = 0; mi < 4; ++mi) {
            int r = mi * 16 + lrow;
            int c = swz(r, quad);
            ax[mi] = *(const frag_ab*)&As_x[r][c];
            aa[mi] = *(const frag_ab*)&As_a[r][c];
        }
        #pragma unroll
        for (int ni = 0; ni < 2; ++ni) {
            int r = wn + ni * 16 + lrow;
            int c = swz(r, quad);
            bg[ni] = *(const frag_ab*)&Bs[0][r][c];
            br[ni] = *(const frag_ab*)&Bs[1][r][c];
            bh[ni] = *(const frag_ab*)&Bs[2][r][c];
        }
        #pragma unroll
        for (int mi = 0; mi < 4; ++mi)
            #pragma unroll
            for (int ni = 0; ni < 2; ++ni) {
                acc[0][mi][ni] = __builtin_amdgcn_mfma_f32_16x16x32_bf16(aa[mi], bg[ni], acc[0][mi][ni], 0, 0, 0);
                acc[1][mi][ni] = __builtin_amdgcn_mfma_f32_16x16x32_bf16(ax[mi], br[ni], acc[1][mi][ni], 0, 0, 0);
                acc[2][mi][ni] = __builtin_amdgcn_mfma_f32_16x16x32_bf16(ax[mi], bh[ni], acc[2][mi][ni], 0, 0, 0);
            }
        __syncthreads();
    }

    #pragma unroll
    for (int mi = 0; mi < 4; ++mi)
        #pragma unroll
        for (int ni = 0; ni < 2; ++ni)
            #pragma unroll
            for (int i = 0; i < 4; ++i) {
                int grow = m0 + mi * 16 + quad * 4 + i;
                if (grow >= n) continue;
                float h = acc[2][mi][ni][i];
                float g = 1.0f / (1.0f + __expf(-h));
                float v = g * acc[0][mi][ni][i] + (1.0f - g) * acc[1][mi][ni][i];
                v = v >= 0.0f ? v : 0.01f * v;
                out[((size_t)f * n + grow) * FEAT + o0 + wn + ni * 16 + lrow] = v;
            }
}

// ---------------- launcher ----------------

static inline size_t align_up(size_t v, size_t a) { return (v + a - 1) & ~(a - 1); }

extern "C" void kernel_launch(void* const* d_in, const int* in_sizes, int n_in,
                              void* d_out, int out_size, void* d_ws, size_t ws_size,
                              hipStream_t stream) {
    const float* x  = (const float*)d_in[0];
    const int*   ei = (const int*)d_in[1];
    const float* ew = (const float*)d_in[2];
    const float* Wg = (const float*)d_in[3];
    const float* Wr = (const float*)d_in[4];
    const float* Wh = (const float*)d_in[5];
    float* out = (float*)d_out;

    const int n = in_sizes[0] / (NFIELD * FEAT);   // 20000
    const int E = in_sizes[2];                     // 320000

    char* base = (char*)d_ws;
    size_t off = 0;
    float* dnrm   = (float*)(base + off); off = align_up(off + (size_t)n * 4, 256);
    int*   count  = (int*)  (base + off); off = align_up(off + (size_t)n * 4, 256);
    int*   rowptr = (int*)  (base + off); off = align_up(off + (size_t)(n + 1) * 4, 256);
    int*   cursor = (int*)  (base + off); off = align_up(off + (size_t)n * 4, 256);
    int2*  erec   = (int2*) (base + off); off = align_up(off + (size_t)E * 8, 256);
    unsigned short* wgT = (unsigned short*)(base + off); off = align_up(off + (size_t)NFIELD * FEAT * FEAT * 2, 256);
    unsigned short* wrT = (unsigned short*)(base + off); off = align_up(off + (size_t)NFIELD * FEAT * FEAT * 2, 256);
    unsigned short* whT = (unsigned short*)(base + off); off = align_up(off + (size_t)NFIELD * FEAT * FEAT * 2, 256);
    size_t fixed = off;

    const size_t per_field = (size_t)n * FEAT * 2;   // bf16
    int fl;
    if (ws_size >= fixed + 2 * (size_t)NFIELD * per_field + 1024) fl = NFIELD;
    else fl = 1;
    unsigned short* xb  = (unsigned short*)(base + fixed);
    unsigned short* xab = (unsigned short*)(base + align_up(fixed + (size_t)fl * per_field, 256));

    const int* col = ei + E;

    int gblocks = (n + 3) / 4;          // 4 waves per 256-thread block
    dim3 ggemm((n + BM - 1) / BM, FEAT / BN, fl);

    if (fl == NFIELD) {
        int cnt4 = NFIELD * n * FEAT / 4;
        // fused cooperative prep: zero+cvt_w+cvt_x | count | scan | fill
        void* args[] = {
            (void*)&erec, (void*)&dnrm, (void*)&count, (void*)&rowptr, (void*)&cursor,
            (void*)&ei, (void*)&ew, (void*)&x, (void*)&xb,
            (void*)&Wg, (void*)&Wr, (void*)&Wh,
            (void*)&wgT, (void*)&wrT, (void*)&whT,
            (void*)&n, (void*)&E, (void*)&cnt4
        };
        hipLaunchCooperativeKernel((const void*)k_prep, dim3(1024), dim3(256),
                                   args, 0, stream);
        k_gather<<<gblocks, 256, 0, stream>>>(erec, dnrm, rowptr, xb, xab, n, NFIELD);
        k_gemm_mfma<<<ggemm, 256, 0, stream>>>(xb, xab, wgT, wrT, whT, out, n, 0);
    } else {
        for (int f = 0; f < NFIELD; ++f) {
            int cnt4 = n * FEAT / 4;
            k_zero <<<(n + 255) / 256, 256, 0, stream>>>(dnrm, count, n);
            k_count<<<(E + 255) / 256, 256, 0, stream>>>(col, ew, dnrm, count, E);
            k_scan <<<1, SCAN_T, 0, stream>>>(count, dnrm, rowptr, cursor, n, E);
            k_fill <<<(E + 255) / 256, 256, 0, stream>>>(ei, ew, dnrm, cursor, erec, E);
            k_cvt_w<<<(NFIELD * FEAT * FEAT + 255) / 256, 256, 0, stream>>>(Wg, Wr, Wh, wgT, wrT, whT);
            k_cvt_x<<<(cnt4 + 255) / 256, 256, 0, stream>>>(x + (size_t)f * n * FEAT, xb, cnt4);
            k_gather<<<gblocks, 256, 0, stream>>>(erec, dnrm, rowptr, xb, xab, n, 1);
            k_gemm_mfma<<<ggemm, 256, 0, stream>>>(xb, xab, wgT, wrT, whT, out, n, f);
        }
    }
}

// Round 5
// 400.462 us; speedup vs baseline: 1.7899x; 1.7899x over previous
//
#include <hip/hip_runtime.h>
#include <math.h>

#define NFIELD 3
#define FEAT 256   // D == O == 256

typedef __attribute__((ext_vector_type(8))) short frag_ab;   // 8 bf16 (4 VGPRs)
typedef __attribute__((ext_vector_type(4))) float frag_cd;   // 4 fp32 acc

__device__ __forceinline__ unsigned short f2bf(float f) {
    unsigned int u = __float_as_uint(f);
    u = (u + 0x7fffu + ((u >> 16) & 1u)) >> 16;   // RNE
    return (unsigned short)u;
}
__device__ __forceinline__ float bf2f(unsigned short b) {
    return __uint_as_float(((unsigned int)b) << 16);
}

// ---------------- fused independent prep: zero + cvt_w + cvt_x ----------------
// R5: no grid.sync (R4 showed ~140us per sync at 1024 blocks). These three
// ops don't communicate, so one plain kernel replaces three dispatches.
// x layout converted to INTERLEAVED [node][field][feat] (1536B per node blob)
// so gather reads one contiguous stream per edge instead of 3 scattered rows.
__global__ __launch_bounds__(256) void k_prep0(
        float* __restrict__ dnrm, int* __restrict__ count, int n,
        const float* __restrict__ Wg, const float* __restrict__ Wr,
        const float* __restrict__ Wh,
        unsigned short* __restrict__ wgT, unsigned short* __restrict__ wrT,
        unsigned short* __restrict__ whT,
        const float* __restrict__ x, unsigned short* __restrict__ xb, int nfld) {
    int gtid = blockIdx.x * 256 + threadIdx.x;
    int gsz  = gridDim.x * 256;

    for (int i = gtid; i < n; i += gsz) { dnrm[i] = 2.0f; count[i] = 0; }

    for (int i = gtid; i < NFIELD * FEAT * FEAT; i += gsz) {
        int f = i >> 16;
        int r = i & 0xffff;
        int d = r >> 8;          // k index in source row-major [d][o]
        int o = r & 255;
        int tdst = (f << 16) | (o << 8) | d;
        wgT[tdst] = f2bf(Wg[i]);
        whT[tdst] = f2bf(Wh[i]);
        wrT[i]    = f2bf(Wr[i]);   // already [o][k]
    }

    int nq = n * (FEAT / 4);              // float4 chunks per field
    int cnt4 = nfld * nq;
    for (int i = gtid; i < cnt4; i += gsz) {
        int f = i / nq;
        int r = i - f * nq;
        int node = r >> 6;
        int q = r & 63;
        float4 v = *((const float4*)x + i);
        ushort4 o;
        o.x = f2bf(v.x); o.y = f2bf(v.y); o.z = f2bf(v.z); o.w = f2bf(v.w);
        ((ushort4*)xb)[((size_t)node * nfld + f) * 64 + q] = o;
    }
}

// ---------------- CSR build: count / scan / fill ----------------

__global__ void k_zero(float* dnrm, int* count, int n) {
    int i = blockIdx.x * blockDim.x + threadIdx.x;
    if (i < n) { dnrm[i] = 2.0f; count[i] = 0; }
}

__global__ void k_count(const int* __restrict__ col, const float* __restrict__ w,
                        float* dnrm, int* count, int E) {
    int e = blockIdx.x * blockDim.x + threadIdx.x;
    if (e < E) {
        int c = col[e];
        atomicAdd(&count[c], 1);
        atomicAdd(&dnrm[c], w[e]);
    }
}

#define SCAN_T 1024
__global__ __launch_bounds__(SCAN_T) void k_scan(const int* __restrict__ count,
        float* dnrm, int* rowptr, int* cursor, int n, int E) {
    __shared__ int part[SCAN_T];
    int t = threadIdx.x;
    int ch = (n + SCAN_T - 1) / SCAN_T;
    int c0 = t * ch, c1 = min(n, c0 + ch);
    int s = 0;
    for (int c = c0; c < c1; ++c) s += count[c];
    part[t] = s;
    __syncthreads();
    for (int off = 1; off < SCAN_T; off <<= 1) {
        int v = (t >= off) ? part[t - off] : 0;
        __syncthreads();
        part[t] += v;
        __syncthreads();
    }
    int base = part[t] - s;
    for (int c = c0; c < c1; ++c) {
        rowptr[c] = base; cursor[c] = base; base += count[c];
        float d = dnrm[c];
        dnrm[c] = d > 0.0f ? rsqrtf(d) : 0.0f;
    }
    if (t == 0) rowptr[n] = E;
}

__global__ void k_fill(const int* __restrict__ ei, const float* __restrict__ ew,
                       const float* __restrict__ dnrm, int* cursor,
                       int2* __restrict__ erec, int E) {
    int e = blockIdx.x * blockDim.x + threadIdx.x;
    if (e < E) {
        int r = ei[e];
        int c = ei[E + e];
        float nm = dnrm[r] * ew[e] * dnrm[c];
        int p = atomicAdd(&cursor[c], 1);
        erec[p] = make_int2(r, __float_as_int(nm));
    }
}

// fallback-path scalar cvt (nfld==1 layout is identical to linear)
__global__ void k_cvt_x(const float* __restrict__ src, unsigned short* __restrict__ dst,
                        int count4) {
    int i = blockIdx.x * blockDim.x + threadIdx.x;
    if (i >= count4) return;
    float4 v = *((const float4*)src + i);
    ushort4 o;
    o.x = f2bf(v.x); o.y = f2bf(v.y); o.z = f2bf(v.z); o.w = f2bf(v.w);
    *((ushort4*)dst + i) = o;
}

__global__ void k_cvt_w(const float* __restrict__ Wg, const float* __restrict__ Wr,
                        const float* __restrict__ Wh,
                        unsigned short* __restrict__ wgT, unsigned short* __restrict__ wrT,
                        unsigned short* __restrict__ whT) {
    int i = blockIdx.x * blockDim.x + threadIdx.x;
    if (i >= NFIELD * FEAT * FEAT) return;
    int f = i >> 16;
    int r = i & 0xffff;
    int d = r >> 8;
    int o = r & 255;
    int tdst = (f << 16) | (o << 8) | d;
    wgT[tdst] = f2bf(Wg[i]);
    whT[tdst] = f2bf(Wh[i]);
    wrT[i]    = f2bf(Wr[i]);
}

// ---------------- gather (R1 form, interleaved layout) ----------------
// xa[c,fl,:] = 2*dinv_c^2 * x[c,fl,:] + sum_e nrm_e * x[src_e,fl,:]
// one wave per destination node; 4-edge unroll -> 12 independent row loads in
// flight; 16B-aligned int4 fetch of record pairs (peel odd beg). Interleaved
// [node][field][feat]: one edge reads a contiguous 1536B blob (field offsets
// are immediates), better LLC/DRAM locality for identical byte count.
__global__ void k_gather(const int2* __restrict__ erec,
                         const float* __restrict__ dnrm, const int* __restrict__ rowptr,
                         const unsigned short* __restrict__ xb,
                         unsigned short* __restrict__ xab,
                         int n, int fl_count) {
    int wid  = blockIdx.x * (blockDim.x >> 6) + (threadIdx.x >> 6);
    int lane = threadIdx.x & 63;
    if (wid >= n) return;
    int c = wid;
    int beg = rowptr[c], end = rowptr[c + 1];
    float dc = dnrm[c];
    float s  = 2.0f * dc * dc;
    const size_t stride = (size_t)fl_count * FEAT;   // 768 (main) or 256 (fallback)

    float acc[NFIELD][4];
    const unsigned short* pc = xb + (size_t)c * stride;
    #pragma unroll
    for (int fl = 0; fl < NFIELD; ++fl) {
        if (fl >= fl_count) break;
        ushort4 v = ((const ushort4*)(pc + fl * FEAT))[lane];
        acc[fl][0] = s * bf2f(v.x); acc[fl][1] = s * bf2f(v.y);
        acc[fl][2] = s * bf2f(v.z); acc[fl][3] = s * bf2f(v.w);
    }

    int i = beg;
    if (fl_count == NFIELD) {
        if ((i & 1) && i < end) {
            int2 ra = erec[i];
            const unsigned short* pa = xb + (size_t)ra.x * (NFIELD * FEAT);
            float na = __int_as_float(ra.y);
            ushort4 va0 = ((const ushort4*)pa)[lane];
            ushort4 va1 = ((const ushort4*)(pa + FEAT))[lane];
            ushort4 va2 = ((const ushort4*)(pa + 2 * FEAT))[lane];
            acc[0][0] += na * bf2f(va0.x); acc[0][1] += na * bf2f(va0.y);
            acc[0][2] += na * bf2f(va0.z); acc[0][3] += na * bf2f(va0.w);
            acc[1][0] += na * bf2f(va1.x); acc[1][1] += na * bf2f(va1.y);
            acc[1][2] += na * bf2f(va1.z); acc[1][3] += na * bf2f(va1.w);
            acc[2][0] += na * bf2f(va2.x); acc[2][1] += na * bf2f(va2.y);
            acc[2][2] += na * bf2f(va2.z); acc[2][3] += na * bf2f(va2.w);
            ++i;
        }
        for (; i + 3 < end; i += 4) {
            int4 qa = *(const int4*)&erec[i];
            int4 qb = *(const int4*)&erec[i + 2];
            const unsigned short* p0 = xb + (size_t)qa.x * (NFIELD * FEAT);
            const unsigned short* p1 = xb + (size_t)qa.z * (NFIELD * FEAT);
            const unsigned short* p2 = xb + (size_t)qb.x * (NFIELD * FEAT);
            const unsigned short* p3 = xb + (size_t)qb.z * (NFIELD * FEAT);
            float n0 = __int_as_float(qa.y);
            float n1 = __int_as_float(qa.w);
            float n2 = __int_as_float(qb.y);
            float n3 = __int_as_float(qb.w);
            ushort4 v[4][NFIELD];
            v[0][0] = ((const ushort4*)p0)[lane];
            v[1][0] = ((const ushort4*)p1)[lane];
            v[2][0] = ((const ushort4*)p2)[lane];
            v[3][0] = ((const ushort4*)p3)[lane];
            v[0][1] = ((const ushort4*)(p0 + FEAT))[lane];
            v[1][1] = ((const ushort4*)(p1 + FEAT))[lane];
            v[2][1] = ((const ushort4*)(p2 + FEAT))[lane];
            v[3][1] = ((const ushort4*)(p3 + FEAT))[lane];
            v[0][2] = ((const ushort4*)(p0 + 2 * FEAT))[lane];
            v[1][2] = ((const ushort4*)(p1 + 2 * FEAT))[lane];
            v[2][2] = ((const ushort4*)(p2 + 2 * FEAT))[lane];
            v[3][2] = ((const ushort4*)(p3 + 2 * FEAT))[lane];
            #pragma unroll
            for (int fl = 0; fl < NFIELD; ++fl) {
                acc[fl][0] += n0 * bf2f(v[0][fl].x) + n1 * bf2f(v[1][fl].x)
                            + n2 * bf2f(v[2][fl].x) + n3 * bf2f(v[3][fl].x);
                acc[fl][1] += n0 * bf2f(v[0][fl].y) + n1 * bf2f(v[1][fl].y)
                            + n2 * bf2f(v[2][fl].y) + n3 * bf2f(v[3][fl].y);
                acc[fl][2] += n0 * bf2f(v[0][fl].z) + n1 * bf2f(v[1][fl].z)
                            + n2 * bf2f(v[2][fl].z) + n3 * bf2f(v[3][fl].z);
                acc[fl][3] += n0 * bf2f(v[0][fl].w) + n1 * bf2f(v[1][fl].w)
                            + n2 * bf2f(v[2][fl].w) + n3 * bf2f(v[3][fl].w);
            }
        }
        for (; i + 1 < end; i += 2) {
            int4 qa = *(const int4*)&erec[i];
            const unsigned short* pa = xb + (size_t)qa.x * (NFIELD * FEAT);
            const unsigned short* pb = xb + (size_t)qa.z * (NFIELD * FEAT);
            float na = __int_as_float(qa.y);
            float nb = __int_as_float(qa.w);
            ushort4 va0 = ((const ushort4*)pa)[lane];
            ushort4 vb0 = ((const ushort4*)pb)[lane];
            ushort4 va1 = ((const ushort4*)(pa + FEAT))[lane];
            ushort4 vb1 = ((const ushort4*)(pb + FEAT))[lane];
            ushort4 va2 = ((const ushort4*)(pa + 2 * FEAT))[lane];
            ushort4 vb2 = ((const ushort4*)(pb + 2 * FEAT))[lane];
            acc[0][0] += na * bf2f(va0.x) + nb * bf2f(vb0.x);
            acc[0][1] += na * bf2f(va0.y) + nb * bf2f(vb0.y);
            acc[0][2] += na * bf2f(va0.z) + nb * bf2f(vb0.z);
            acc[0][3] += na * bf2f(va0.w) + nb * bf2f(vb0.w);
            acc[1][0] += na * bf2f(va1.x) + nb * bf2f(vb1.x);
            acc[1][1] += na * bf2f(va1.y) + nb * bf2f(vb1.y);
            acc[1][2] += na * bf2f(va1.z) + nb * bf2f(vb1.z);
            acc[1][3] += na * bf2f(va1.w) + nb * bf2f(vb1.w);
            acc[2][0] += na * bf2f(va2.x) + nb * bf2f(vb2.x);
            acc[2][1] += na * bf2f(va2.y) + nb * bf2f(vb2.y);
            acc[2][2] += na * bf2f(va2.z) + nb * bf2f(vb2.z);
            acc[2][3] += na * bf2f(va2.w) + nb * bf2f(vb2.w);
        }
        for (; i < end; ++i) {
            int2 ra = erec[i];
            const unsigned short* pa = xb + (size_t)ra.x * (NFIELD * FEAT);
            float na = __int_as_float(ra.y);
            ushort4 va0 = ((const ushort4*)pa)[lane];
            ushort4 va1 = ((const ushort4*)(pa + FEAT))[lane];
            ushort4 va2 = ((const ushort4*)(pa + 2 * FEAT))[lane];
            acc[0][0] += na * bf2f(va0.x); acc[0][1] += na * bf2f(va0.y);
            acc[0][2] += na * bf2f(va0.z); acc[0][3] += na * bf2f(va0.w);
            acc[1][0] += na * bf2f(va1.x); acc[1][1] += na * bf2f(va1.y);
            acc[1][2] += na * bf2f(va1.z); acc[1][3] += na * bf2f(va1.w);
            acc[2][0] += na * bf2f(va2.x); acc[2][1] += na * bf2f(va2.y);
            acc[2][2] += na * bf2f(va2.z); acc[2][3] += na * bf2f(va2.w);
        }
    } else {
        for (; i < end; ++i) {
            int2 ra = erec[i];
            const unsigned short* pa = xb + (size_t)ra.x * FEAT;
            float na = __int_as_float(ra.y);
            ushort4 va0 = ((const ushort4*)pa)[lane];
            acc[0][0] += na * bf2f(va0.x); acc[0][1] += na * bf2f(va0.y);
            acc[0][2] += na * bf2f(va0.z); acc[0][3] += na * bf2f(va0.w);
        }
    }

    unsigned short* po = xab + (size_t)c * stride;
    #pragma unroll
    for (int fl = 0; fl < NFIELD; ++fl) {
        if (fl >= fl_count) break;
        ushort4 o;
        o.x = f2bf(acc[fl][0]); o.y = f2bf(acc[fl][1]);
        o.z = f2bf(acc[fl][2]); o.w = f2bf(acc[fl][3]);
        ((ushort4*)(po + fl * FEAT))[lane] = o;
    }
}

// ---------------- MFMA GEMM + highway + leaky_relu — NO-LDS direct form ----------------
// R5: A-tile (96KB/block, LLC-resident) and weights (1.18MB, L2-hot) are
// cache-served; stage nothing (Common-mistake #7). Each wave loads its MFMA
// fragments directly from global (byte-identical data to the old swizzled-LDS
// path), eliminating both per-K-step barriers, all LDS traffic, and staging
// stores. 14 x 16B loads + 24 MFMAs per K-step, waves fully independent.
#define BM 64
#define BN 128

__global__ __launch_bounds__(256) void k_gemm_mfma(
    const unsigned short* __restrict__ xb, const unsigned short* __restrict__ xab,
    const unsigned short* __restrict__ wgT, const unsigned short* __restrict__ wrT,
    const unsigned short* __restrict__ whT,
    float* __restrict__ out, int n, int f_base, int nfld) {

    int fl = blockIdx.z;
    int f  = f_base + fl;
    int m0 = blockIdx.x * BM;
    int o0 = blockIdx.y * BN;
    int t  = threadIdx.x;

    int w    = t >> 6;
    int lane = t & 63;
    int lrow = lane & 15;
    int quad = lane >> 4;
    int wn   = w * 32;      // wave's 32-col window of the 128-wide tile

    const unsigned short* wsrc0 = wgT + ((size_t)f << 16);
    const unsigned short* wsrc1 = wrT + ((size_t)f << 16);
    const unsigned short* wsrc2 = whT + ((size_t)f << 16);

    frag_cd acc[3][4][2];
    #pragma unroll
    for (int s = 0; s < 3; ++s)
        #pragma unroll
        for (int mi = 0; mi < 4; ++mi)
            #pragma unroll
            for (int ni = 0; ni < 2; ++ni)
                acc[s][mi][ni] = (frag_cd){0.f, 0.f, 0.f, 0.f};

    // per-lane fragment base pointers (row-resolved once)
    const unsigned short* pax[4];
    const unsigned short* paa[4];
    #pragma unroll
    for (int mi = 0; mi < 4; ++mi) {
        int m = min(m0 + mi * 16 + lrow, n - 1);    // clamp loads; stores guarded
        size_t off = ((size_t)m * nfld + fl) * FEAT;
        pax[mi] = xb + off;
        paa[mi] = xab + off;
    }
    const unsigned short* pb[3][2];
    #pragma unroll
    for (int ni = 0; ni < 2; ++ni) {
        size_t r = (size_t)(o0 + wn + ni * 16 + lrow) << 8;
        pb[0][ni] = wsrc0 + r;
        pb[1][ni] = wsrc1 + r;
        pb[2][ni] = wsrc2 + r;
    }

    #pragma unroll
    for (int k0 = 0; k0 < FEAT; k0 += 32) {
        int kq = k0 + quad * 8;
        frag_ab ax[4], aa[4], bg[2], br[2], bh[2];
        #pragma unroll
        for (int mi = 0; mi < 4; ++mi) {
            ax[mi] = *(const frag_ab*)(pax[mi] + kq);
            aa[mi] = *(const frag_ab*)(paa[mi] + kq);
        }
        #pragma unroll
        for (int ni = 0; ni < 2; ++ni) {
            bg[ni] = *(const frag_ab*)(pb[0][ni] + kq);
            br[ni] = *(const frag_ab*)(pb[1][ni] + kq);
            bh[ni] = *(const frag_ab*)(pb[2][ni] + kq);
        }
        #pragma unroll
        for (int mi = 0; mi < 4; ++mi)
            #pragma unroll
            for (int ni = 0; ni < 2; ++ni) {
                acc[0][mi][ni] = __builtin_amdgcn_mfma_f32_16x16x32_bf16(aa[mi], bg[ni], acc[0][mi][ni], 0, 0, 0);
                acc[1][mi][ni] = __builtin_amdgcn_mfma_f32_16x16x32_bf16(ax[mi], br[ni], acc[1][mi][ni], 0, 0, 0);
                acc[2][mi][ni] = __builtin_amdgcn_mfma_f32_16x16x32_bf16(ax[mi], bh[ni], acc[2][mi][ni], 0, 0, 0);
            }
    }

    // epilogue: C/D layout col=lane&15, row=quad*4+i (m89/m91-verified)
    #pragma unroll
    for (int mi = 0; mi < 4; ++mi)
        #pragma unroll
        for (int ni = 0; ni < 2; ++ni)
            #pragma unroll
            for (int i = 0; i < 4; ++i) {
                int grow = m0 + mi * 16 + quad * 4 + i;
                if (grow >= n) continue;
                float h = acc[2][mi][ni][i];
                float g = 1.0f / (1.0f + __expf(-h));
                float v = g * acc[0][mi][ni][i] + (1.0f - g) * acc[1][mi][ni][i];
                v = v >= 0.0f ? v : 0.01f * v;
                out[((size_t)f * n + grow) * FEAT + o0 + wn + ni * 16 + lrow] = v;
            }
}

// ---------------- launcher ----------------

static inline size_t align_up(size_t v, size_t a) { return (v + a - 1) & ~(a - 1); }

extern "C" void kernel_launch(void* const* d_in, const int* in_sizes, int n_in,
                              void* d_out, int out_size, void* d_ws, size_t ws_size,
                              hipStream_t stream) {
    const float* x  = (const float*)d_in[0];
    const int*   ei = (const int*)d_in[1];
    const float* ew = (const float*)d_in[2];
    const float* Wg = (const float*)d_in[3];
    const float* Wr = (const float*)d_in[4];
    const float* Wh = (const float*)d_in[5];
    float* out = (float*)d_out;

    const int n = in_sizes[0] / (NFIELD * FEAT);   // 20000
    const int E = in_sizes[2];                     // 320000

    char* base = (char*)d_ws;
    size_t off = 0;
    float* dnrm   = (float*)(base + off); off = align_up(off + (size_t)n * 4, 256);
    int*   count  = (int*)  (base + off); off = align_up(off + (size_t)n * 4, 256);
    int*   rowptr = (int*)  (base + off); off = align_up(off + (size_t)(n + 1) * 4, 256);
    int*   cursor = (int*)  (base + off); off = align_up(off + (size_t)n * 4, 256);
    int2*  erec   = (int2*) (base + off); off = align_up(off + (size_t)E * 8, 256);
    unsigned short* wgT = (unsigned short*)(base + off); off = align_up(off + (size_t)NFIELD * FEAT * FEAT * 2, 256);
    unsigned short* wrT = (unsigned short*)(base + off); off = align_up(off + (size_t)NFIELD * FEAT * FEAT * 2, 256);
    unsigned short* whT = (unsigned short*)(base + off); off = align_up(off + (size_t)NFIELD * FEAT * FEAT * 2, 256);
    size_t fixed = off;

    const size_t per_field = (size_t)n * FEAT * 2;   // bf16
    int fl;
    if (ws_size >= fixed + 2 * (size_t)NFIELD * per_field + 1024) fl = NFIELD;
    else fl = 1;
    unsigned short* xb  = (unsigned short*)(base + fixed);
    unsigned short* xab = (unsigned short*)(base + align_up(fixed + (size_t)fl * per_field, 256));

    const int* col = ei + E;

    int gblocks = (n + 3) / 4;          // 4 waves per 256-thread block
    dim3 ggemm((n + BM - 1) / BM, FEAT / BN, fl);

    if (fl == NFIELD) {
        // 6 dispatches: prep0 | count | scan | fill | gather | gemm
        k_prep0<<<2048, 256, 0, stream>>>(dnrm, count, n, Wg, Wr, Wh,
                                          wgT, wrT, whT, x, xb, NFIELD);
        k_count<<<(E + 255) / 256, 256, 0, stream>>>(col, ew, dnrm, count, E);
        k_scan <<<1, SCAN_T, 0, stream>>>(count, dnrm, rowptr, cursor, n, E);
        k_fill <<<(E + 255) / 256, 256, 0, stream>>>(ei, ew, dnrm, cursor, erec, E);
        k_gather<<<gblocks, 256, 0, stream>>>(erec, dnrm, rowptr, xb, xab, n, NFIELD);
        k_gemm_mfma<<<ggemm, 256, 0, stream>>>(xb, xab, wgT, wrT, whT, out, n, 0, NFIELD);
    } else {
        for (int f = 0; f < NFIELD; ++f) {
            int cnt4 = n * FEAT / 4;
            k_zero <<<(n + 255) / 256, 256, 0, stream>>>(dnrm, count, n);
            k_count<<<(E + 255) / 256, 256, 0, stream>>>(col, ew, dnrm, count, E);
            k_scan <<<1, SCAN_T, 0, stream>>>(count, dnrm, rowptr, cursor, n, E);
            k_fill <<<(E + 255) / 256, 256, 0, stream>>>(ei, ew, dnrm, cursor, erec, E);
            k_cvt_w<<<(NFIELD * FEAT * FEAT + 255) / 256, 256, 0, stream>>>(Wg, Wr, Wh, wgT, wrT, whT);
            k_cvt_x<<<(cnt4 + 255) / 256, 256, 0, stream>>>(x + (size_t)f * n * FEAT, xb, cnt4);
            k_gather<<<gblocks, 256, 0, stream>>>(erec, dnrm, rowptr, xb, xab, n, 1);
            k_gemm_mfma<<<ggemm, 256, 0, stream>>>(xb, xab, wgT, wrT, whT, out, n, f, 1);
        }
    }
}

// Round 6
// 351.428 us; speedup vs baseline: 2.0397x; 1.1395x over previous
//
#include <hip/hip_runtime.h>
#include <math.h>

#define NFIELD 3
#define FEAT 256   // D == O == 256

typedef __attribute__((ext_vector_type(8))) short frag_ab;   // 8 bf16 (4 VGPRs)
typedef __attribute__((ext_vector_type(4))) float frag_cd;   // 4 fp32 acc

__device__ __forceinline__ unsigned short f2bf(float f) {
    unsigned int u = __float_as_uint(f);
    u = (u + 0x7fffu + ((u >> 16) & 1u)) >> 16;   // RNE
    return (unsigned short)u;
}
__device__ __forceinline__ float bf2f(unsigned short b) {
    return __uint_as_float(((unsigned int)b) << 16);
}

// ---------------- fused independent prep: zero + cvt_w + cvt_x ----------------
// (R5, kept) x converted to INTERLEAVED [node][field][feat].
__global__ __launch_bounds__(256) void k_prep0(
        float* __restrict__ dnrm, int* __restrict__ count, int n,
        const float* __restrict__ Wg, const float* __restrict__ Wr,
        const float* __restrict__ Wh,
        unsigned short* __restrict__ wgT, unsigned short* __restrict__ wrT,
        unsigned short* __restrict__ whT,
        const float* __restrict__ x, unsigned short* __restrict__ xb, int nfld) {
    int gtid = blockIdx.x * 256 + threadIdx.x;
    int gsz  = gridDim.x * 256;

    for (int i = gtid; i < n; i += gsz) { dnrm[i] = 2.0f; count[i] = 0; }

    for (int i = gtid; i < NFIELD * FEAT * FEAT; i += gsz) {
        int f = i >> 16;
        int r = i & 0xffff;
        int d = r >> 8;          // k index in source row-major [d][o]
        int o = r & 255;
        int tdst = (f << 16) | (o << 8) | d;
        wgT[tdst] = f2bf(Wg[i]);
        whT[tdst] = f2bf(Wh[i]);
        wrT[i]    = f2bf(Wr[i]);   // already [o][k]
    }

    int nq = n * (FEAT / 4);              // float4 chunks per field
    int cnt4 = nfld * nq;
    for (int i = gtid; i < cnt4; i += gsz) {
        int f = i / nq;
        int r = i - f * nq;
        int node = r >> 6;
        int q = r & 63;
        float4 v = *((const float4*)x + i);
        ushort4 o;
        o.x = f2bf(v.x); o.y = f2bf(v.y); o.z = f2bf(v.z); o.w = f2bf(v.w);
        ((ushort4*)xb)[((size_t)node * nfld + f) * 64 + q] = o;
    }
}

// ---------------- CSR build: count / scan / fill ----------------

__global__ void k_zero(float* dnrm, int* count, int n) {
    int i = blockIdx.x * blockDim.x + threadIdx.x;
    if (i < n) { dnrm[i] = 2.0f; count[i] = 0; }
}

__global__ void k_count(const int* __restrict__ col, const float* __restrict__ w,
                        float* dnrm, int* count, int E) {
    int e = blockIdx.x * blockDim.x + threadIdx.x;
    if (e < E) {
        int c = col[e];
        atomicAdd(&count[c], 1);
        atomicAdd(&dnrm[c], w[e]);
    }
}

#define SCAN_T 1024
__global__ __launch_bounds__(SCAN_T) void k_scan(const int* __restrict__ count,
        float* dnrm, int* rowptr, int* cursor, int n, int E) {
    __shared__ int part[SCAN_T];
    int t = threadIdx.x;
    int ch = (n + SCAN_T - 1) / SCAN_T;
    int c0 = t * ch, c1 = min(n, c0 + ch);
    int s = 0;
    for (int c = c0; c < c1; ++c) s += count[c];
    part[t] = s;
    __syncthreads();
    for (int off = 1; off < SCAN_T; off <<= 1) {
        int v = (t >= off) ? part[t - off] : 0;
        __syncthreads();
        part[t] += v;
        __syncthreads();
    }
    int base = part[t] - s;
    for (int c = c0; c < c1; ++c) {
        rowptr[c] = base; cursor[c] = base; base += count[c];
        float d = dnrm[c];
        dnrm[c] = d > 0.0f ? rsqrtf(d) : 0.0f;
    }
    if (t == 0) rowptr[n] = E;
}

__global__ void k_fill(const int* __restrict__ ei, const float* __restrict__ ew,
                       const float* __restrict__ dnrm, int* cursor,
                       int2* __restrict__ erec, int E) {
    int e = blockIdx.x * blockDim.x + threadIdx.x;
    if (e < E) {
        int r = ei[e];
        int c = ei[E + e];
        float nm = dnrm[r] * ew[e] * dnrm[c];
        int p = atomicAdd(&cursor[c], 1);
        erec[p] = make_int2(r, __float_as_int(nm));
    }
}

// fallback-path scalar cvt (nfld==1 layout is identical to linear)
__global__ void k_cvt_x(const float* __restrict__ src, unsigned short* __restrict__ dst,
                        int count4) {
    int i = blockIdx.x * blockDim.x + threadIdx.x;
    if (i >= count4) return;
    float4 v = *((const float4*)src + i);
    ushort4 o;
    o.x = f2bf(v.x); o.y = f2bf(v.y); o.z = f2bf(v.z); o.w = f2bf(v.w);
    *((ushort4*)dst + i) = o;
}

__global__ void k_cvt_w(const float* __restrict__ Wg, const float* __restrict__ Wr,
                        const float* __restrict__ Wh,
                        unsigned short* __restrict__ wgT, unsigned short* __restrict__ wrT,
                        unsigned short* __restrict__ whT) {
    int i = blockIdx.x * blockDim.x + threadIdx.x;
    if (i >= NFIELD * FEAT * FEAT) return;
    int f = i >> 16;
    int r = i & 0xffff;
    int d = r >> 8;
    int o = r & 255;
    int tdst = (f << 16) | (o << 8) | d;
    wgT[tdst] = f2bf(Wg[i]);
    whT[tdst] = f2bf(Wh[i]);
    wrT[i]    = f2bf(Wr[i]);
}

// ---------------- gather (R1 form, interleaved layout — kept from R5) ----------------
__global__ void k_gather(const int2* __restrict__ erec,
                         const float* __restrict__ dnrm, const int* __restrict__ rowptr,
                         const unsigned short* __restrict__ xb,
                         unsigned short* __restrict__ xab,
                         int n, int fl_count) {
    int wid  = blockIdx.x * (blockDim.x >> 6) + (threadIdx.x >> 6);
    int lane = threadIdx.x & 63;
    if (wid >= n) return;
    int c = wid;
    int beg = rowptr[c], end = rowptr[c + 1];
    float dc = dnrm[c];
    float s  = 2.0f * dc * dc;
    const size_t stride = (size_t)fl_count * FEAT;   // 768 (main) or 256 (fallback)

    float acc[NFIELD][4];
    const unsigned short* pc = xb + (size_t)c * stride;
    #pragma unroll
    for (int fl = 0; fl < NFIELD; ++fl) {
        if (fl >= fl_count) break;
        ushort4 v = ((const ushort4*)(pc + fl * FEAT))[lane];
        acc[fl][0] = s * bf2f(v.x); acc[fl][1] = s * bf2f(v.y);
        acc[fl][2] = s * bf2f(v.z); acc[fl][3] = s * bf2f(v.w);
    }

    int i = beg;
    if (fl_count == NFIELD) {
        if ((i & 1) && i < end) {
            int2 ra = erec[i];
            const unsigned short* pa = xb + (size_t)ra.x * (NFIELD * FEAT);
            float na = __int_as_float(ra.y);
            ushort4 va0 = ((const ushort4*)pa)[lane];
            ushort4 va1 = ((const ushort4*)(pa + FEAT))[lane];
            ushort4 va2 = ((const ushort4*)(pa + 2 * FEAT))[lane];
            acc[0][0] += na * bf2f(va0.x); acc[0][1] += na * bf2f(va0.y);
            acc[0][2] += na * bf2f(va0.z); acc[0][3] += na * bf2f(va0.w);
            acc[1][0] += na * bf2f(va1.x); acc[1][1] += na * bf2f(va1.y);
            acc[1][2] += na * bf2f(va1.z); acc[1][3] += na * bf2f(va1.w);
            acc[2][0] += na * bf2f(va2.x); acc[2][1] += na * bf2f(va2.y);
            acc[2][2] += na * bf2f(va2.z); acc[2][3] += na * bf2f(va2.w);
            ++i;
        }
        for (; i + 3 < end; i += 4) {
            int4 qa = *(const int4*)&erec[i];
            int4 qb = *(const int4*)&erec[i + 2];
            const unsigned short* p0 = xb + (size_t)qa.x * (NFIELD * FEAT);
            const unsigned short* p1 = xb + (size_t)qa.z * (NFIELD * FEAT);
            const unsigned short* p2 = xb + (size_t)qb.x * (NFIELD * FEAT);
            const unsigned short* p3 = xb + (size_t)qb.z * (NFIELD * FEAT);
            float n0 = __int_as_float(qa.y);
            float n1 = __int_as_float(qa.w);
            float n2 = __int_as_float(qb.y);
            float n3 = __int_as_float(qb.w);
            ushort4 v[4][NFIELD];
            v[0][0] = ((const ushort4*)p0)[lane];
            v[1][0] = ((const ushort4*)p1)[lane];
            v[2][0] = ((const ushort4*)p2)[lane];
            v[3][0] = ((const ushort4*)p3)[lane];
            v[0][1] = ((const ushort4*)(p0 + FEAT))[lane];
            v[1][1] = ((const ushort4*)(p1 + FEAT))[lane];
            v[2][1] = ((const ushort4*)(p2 + FEAT))[lane];
            v[3][1] = ((const ushort4*)(p3 + FEAT))[lane];
            v[0][2] = ((const ushort4*)(p0 + 2 * FEAT))[lane];
            v[1][2] = ((const ushort4*)(p1 + 2 * FEAT))[lane];
            v[2][2] = ((const ushort4*)(p2 + 2 * FEAT))[lane];
            v[3][2] = ((const ushort4*)(p3 + 2 * FEAT))[lane];
            #pragma unroll
            for (int fl = 0; fl < NFIELD; ++fl) {
                acc[fl][0] += n0 * bf2f(v[0][fl].x) + n1 * bf2f(v[1][fl].x)
                            + n2 * bf2f(v[2][fl].x) + n3 * bf2f(v[3][fl].x);
                acc[fl][1] += n0 * bf2f(v[0][fl].y) + n1 * bf2f(v[1][fl].y)
                            + n2 * bf2f(v[2][fl].y) + n3 * bf2f(v[3][fl].y);
                acc[fl][2] += n0 * bf2f(v[0][fl].z) + n1 * bf2f(v[1][fl].z)
                            + n2 * bf2f(v[2][fl].z) + n3 * bf2f(v[3][fl].z);
                acc[fl][3] += n0 * bf2f(v[0][fl].w) + n1 * bf2f(v[1][fl].w)
                            + n2 * bf2f(v[2][fl].w) + n3 * bf2f(v[3][fl].w);
            }
        }
        for (; i + 1 < end; i += 2) {
            int4 qa = *(const int4*)&erec[i];
            const unsigned short* pa = xb + (size_t)qa.x * (NFIELD * FEAT);
            const unsigned short* pb = xb + (size_t)qa.z * (NFIELD * FEAT);
            float na = __int_as_float(qa.y);
            float nb = __int_as_float(qa.w);
            ushort4 va0 = ((const ushort4*)pa)[lane];
            ushort4 vb0 = ((const ushort4*)pb)[lane];
            ushort4 va1 = ((const ushort4*)(pa + FEAT))[lane];
            ushort4 vb1 = ((const ushort4*)(pb + FEAT))[lane];
            ushort4 va2 = ((const ushort4*)(pa + 2 * FEAT))[lane];
            ushort4 vb2 = ((const ushort4*)(pb + 2 * FEAT))[lane];
            acc[0][0] += na * bf2f(va0.x) + nb * bf2f(vb0.x);
            acc[0][1] += na * bf2f(va0.y) + nb * bf2f(vb0.y);
            acc[0][2] += na * bf2f(va0.z) + nb * bf2f(vb0.z);
            acc[0][3] += na * bf2f(va0.w) + nb * bf2f(vb0.w);
            acc[1][0] += na * bf2f(va1.x) + nb * bf2f(vb1.x);
            acc[1][1] += na * bf2f(va1.y) + nb * bf2f(vb1.y);
            acc[1][2] += na * bf2f(va1.z) + nb * bf2f(vb1.z);
            acc[1][3] += na * bf2f(va1.w) + nb * bf2f(vb1.w);
            acc[2][0] += na * bf2f(va2.x) + nb * bf2f(vb2.x);
            acc[2][1] += na * bf2f(va2.y) + nb * bf2f(vb2.y);
            acc[2][2] += na * bf2f(va2.z) + nb * bf2f(vb2.z);
            acc[2][3] += na * bf2f(va2.w) + nb * bf2f(vb2.w);
        }
        for (; i < end; ++i) {
            int2 ra = erec[i];
            const unsigned short* pa = xb + (size_t)ra.x * (NFIELD * FEAT);
            float na = __int_as_float(ra.y);
            ushort4 va0 = ((const ushort4*)pa)[lane];
            ushort4 va1 = ((const ushort4*)(pa + FEAT))[lane];
            ushort4 va2 = ((const ushort4*)(pa + 2 * FEAT))[lane];
            acc[0][0] += na * bf2f(va0.x); acc[0][1] += na * bf2f(va0.y);
            acc[0][2] += na * bf2f(va0.z); acc[0][3] += na * bf2f(va0.w);
            acc[1][0] += na * bf2f(va1.x); acc[1][1] += na * bf2f(va1.y);
            acc[1][2] += na * bf2f(va1.z); acc[1][3] += na * bf2f(va1.w);
            acc[2][0] += na * bf2f(va2.x); acc[2][1] += na * bf2f(va2.y);
            acc[2][2] += na * bf2f(va2.z); acc[2][3] += na * bf2f(va2.w);
        }
    } else {
        for (; i < end; ++i) {
            int2 ra = erec[i];
            const unsigned short* pa = xb + (size_t)ra.x * FEAT;
            float na = __int_as_float(ra.y);
            ushort4 va0 = ((const ushort4*)pa)[lane];
            acc[0][0] += na * bf2f(va0.x); acc[0][1] += na * bf2f(va0.y);
            acc[0][2] += na * bf2f(va0.z); acc[0][3] += na * bf2f(va0.w);
        }
    }

    unsigned short* po = xab + (size_t)c * stride;
    #pragma unroll
    for (int fl = 0; fl < NFIELD; ++fl) {
        if (fl >= fl_count) break;
        ushort4 o;
        o.x = f2bf(acc[fl][0]); o.y = f2bf(acc[fl][1]);
        o.z = f2bf(acc[fl][2]); o.w = f2bf(acc[fl][3]);
        ((ushort4*)(po + fl * FEAT))[lane] = o;
    }
}

// ---------------- MFMA GEMM + highway + leaky_relu — LDS form (R1, reverted) ----------------
// R6: R5's no-LDS form was latency-bound (MfmaUtil 7.7%, 118us): per-lane
// fragment loads scatter 16 rows x 512B stride per instruction, MFMA stalls on
// L2 latency. LDS staging IS the latency-hiding mechanism (coalesced bulk
// loads + ds_read), not a traffic opt. Reverted to the proven swizzled-LDS
// structure (36KB/block -> 4 blocks/CU), adapted to interleaved A layout.
#define BM 64
#define BN 128
#define BK 32

__device__ __forceinline__ int swz(int row, int quad) {
    return (quad ^ ((row >> 1) & 3)) * 8;
}

__global__ __launch_bounds__(256) void k_gemm_mfma(
    const unsigned short* __restrict__ xb, const unsigned short* __restrict__ xab,
    const unsigned short* __restrict__ wgT, const unsigned short* __restrict__ wrT,
    const unsigned short* __restrict__ whT,
    float* __restrict__ out, int n, int f_base, int nfld) {

    __shared__ unsigned short As_x[BM][BK];
    __shared__ unsigned short As_a[BM][BK];
    __shared__ unsigned short Bs[3][BN][BK];   // g, r, h

    int fl = blockIdx.z;
    int f  = f_base + fl;
    int m0 = blockIdx.x * BM;
    int o0 = blockIdx.y * BN;
    int t  = threadIdx.x;

    const unsigned short* wsrc0 = wgT + ((size_t)f << 16);
    const unsigned short* wsrc1 = wrT + ((size_t)f << 16);
    const unsigned short* wsrc2 = whT + ((size_t)f << 16);

    int w    = t >> 6;
    int lane = t & 63;
    int lrow = lane & 15;
    int quad = lane >> 4;
    int wn   = w * 32;      // wave's 32-col window of the 128-wide tile

    frag_cd acc[3][4][2];   // stream (g,r,h), mi, ni
    #pragma unroll
    for (int s = 0; s < 3; ++s)
        #pragma unroll
        for (int mi = 0; mi < 4; ++mi)
            #pragma unroll
            for (int ni = 0; ni < 2; ++ni)
                acc[s][mi][ni] = (frag_cd){0.f, 0.f, 0.f, 0.f};

    // A staging: thread t -> row t>>2 (0..63), 16B chunk t&3
    int arow = t >> 2;
    int aq   = (t & 3) * 8;
    int adst = swz(arow, t & 3);
    int am   = min(m0 + arow, n - 1);                 // clamp loads; stores guarded
    size_t arowoff = ((size_t)am * nfld + fl) * FEAT; // interleaved [node][field][feat]

    for (int k0 = 0; k0 < FEAT; k0 += BK) {
        *(uint4*)&As_x[arow][adst] = *(const uint4*)(xb  + arowoff + k0 + aq);
        *(uint4*)&As_a[arow][adst] = *(const uint4*)(xab + arowoff + k0 + aq);
        #pragma unroll
        for (int s = 0; s < 6; ++s) {
            int buf = s >> 1;                          // uniform per unrolled s
            int row = (s & 1) * 64 + (t >> 2);         // 0..127
            const unsigned short* wsrc = (buf == 0) ? wsrc0 : (buf == 1) ? wsrc1 : wsrc2;
            *(uint4*)&Bs[buf][row][swz(row, t & 3)] =
                *(const uint4*)(wsrc + ((o0 + row) << 8) + k0 + aq);
        }
        __syncthreads();

        frag_ab ax[4], aa[4], bg[2], br[2], bh[2];
        #pragma unroll
        for (int mi = 0; mi < 4; ++mi) {
            int r = mi * 16 + lrow;
            int c = swz(r, quad);
            ax[mi] = *(const frag_ab*)&As_x[r][c];
            aa[mi] = *(const frag_ab*)&As_a[r][c];
        }
        #pragma unroll
        for (int ni = 0; ni < 2; ++ni) {
            int r = wn + ni * 16 + lrow;
            int c = swz(r, quad);
            bg[ni] = *(const frag_ab*)&Bs[0][r][c];
            br[ni] = *(const frag_ab*)&Bs[1][r][c];
            bh[ni] = *(const frag_ab*)&Bs[2][r][c];
        }
        #pragma unroll
        for (int mi = 0; mi < 4; ++mi)
            #pragma unroll
            for (int ni = 0; ni < 2; ++ni) {
                acc[0][mi][ni] = __builtin_amdgcn_mfma_f32_16x16x32_bf16(aa[mi], bg[ni], acc[0][mi][ni], 0, 0, 0);
                acc[1][mi][ni] = __builtin_amdgcn_mfma_f32_16x16x32_bf16(ax[mi], br[ni], acc[1][mi][ni], 0, 0, 0);
                acc[2][mi][ni] = __builtin_amdgcn_mfma_f32_16x16x32_bf16(ax[mi], bh[ni], acc[2][mi][ni], 0, 0, 0);
            }
        __syncthreads();
    }

    // epilogue: C/D layout col=lane&15, row=quad*4+i (m89/m91-verified)
    #pragma unroll
    for (int mi = 0; mi < 4; ++mi)
        #pragma unroll
        for (int ni = 0; ni < 2; ++ni)
            #pragma unroll
            for (int i = 0; i < 4; ++i) {
                int grow = m0 + mi * 16 + quad * 4 + i;
                if (grow >= n) continue;
                float h = acc[2][mi][ni][i];
                float g = 1.0f / (1.0f + __expf(-h));
                float v = g * acc[0][mi][ni][i] + (1.0f - g) * acc[1][mi][ni][i];
                v = v >= 0.0f ? v : 0.01f * v;
                out[((size_t)f * n + grow) * FEAT + o0 + wn + ni * 16 + lrow] = v;
            }
}

// ---------------- launcher ----------------

static inline size_t align_up(size_t v, size_t a) { return (v + a - 1) & ~(a - 1); }

extern "C" void kernel_launch(void* const* d_in, const int* in_sizes, int n_in,
                              void* d_out, int out_size, void* d_ws, size_t ws_size,
                              hipStream_t stream) {
    const float* x  = (const float*)d_in[0];
    const int*   ei = (const int*)d_in[1];
    const float* ew = (const float*)d_in[2];
    const float* Wg = (const float*)d_in[3];
    const float* Wr = (const float*)d_in[4];
    const float* Wh = (const float*)d_in[5];
    float* out = (float*)d_out;

    const int n = in_sizes[0] / (NFIELD * FEAT);   // 20000
    const int E = in_sizes[2];                     // 320000

    char* base = (char*)d_ws;
    size_t off = 0;
    float* dnrm   = (float*)(base + off); off = align_up(off + (size_t)n * 4, 256);
    int*   count  = (int*)  (base + off); off = align_up(off + (size_t)n * 4, 256);
    int*   rowptr = (int*)  (base + off); off = align_up(off + (size_t)(n + 1) * 4, 256);
    int*   cursor = (int*)  (base + off); off = align_up(off + (size_t)n * 4, 256);
    int2*  erec   = (int2*) (base + off); off = align_up(off + (size_t)E * 8, 256);
    unsigned short* wgT = (unsigned short*)(base + off); off = align_up(off + (size_t)NFIELD * FEAT * FEAT * 2, 256);
    unsigned short* wrT = (unsigned short*)(base + off); off = align_up(off + (size_t)NFIELD * FEAT * FEAT * 2, 256);
    unsigned short* whT = (unsigned short*)(base + off); off = align_up(off + (size_t)NFIELD * FEAT * FEAT * 2, 256);
    size_t fixed = off;

    const size_t per_field = (size_t)n * FEAT * 2;   // bf16
    int fl;
    if (ws_size >= fixed + 2 * (size_t)NFIELD * per_field + 1024) fl = NFIELD;
    else fl = 1;
    unsigned short* xb  = (unsigned short*)(base + fixed);
    unsigned short* xab = (unsigned short*)(base + align_up(fixed + (size_t)fl * per_field, 256));

    const int* col = ei + E;

    int gblocks = (n + 3) / 4;          // 4 waves per 256-thread block
    dim3 ggemm((n + BM - 1) / BM, FEAT / BN, fl);

    if (fl == NFIELD) {
        // 6 dispatches: prep0 | count | scan | fill | gather | gemm
        k_prep0<<<2048, 256, 0, stream>>>(dnrm, count, n, Wg, Wr, Wh,
                                          wgT, wrT, whT, x, xb, NFIELD);
        k_count<<<(E + 255) / 256, 256, 0, stream>>>(col, ew, dnrm, count, E);
        k_scan <<<1, SCAN_T, 0, stream>>>(count, dnrm, rowptr, cursor, n, E);
        k_fill <<<(E + 255) / 256, 256, 0, stream>>>(ei, ew, dnrm, cursor, erec, E);
        k_gather<<<gblocks, 256, 0, stream>>>(erec, dnrm, rowptr, xb, xab, n, NFIELD);
        k_gemm_mfma<<<ggemm, 256, 0, stream>>>(xb, xab, wgT, wrT, whT, out, n, 0, NFIELD);
    } else {
        for (int f = 0; f < NFIELD; ++f) {
            int cnt4 = n * FEAT / 4;
            k_zero <<<(n + 255) / 256, 256, 0, stream>>>(dnrm, count, n);
            k_count<<<(E + 255) / 256, 256, 0, stream>>>(col, ew, dnrm, count, E);
            k_scan <<<1, SCAN_T, 0, stream>>>(count, dnrm, rowptr, cursor, n, E);
            k_fill <<<(E + 255) / 256, 256, 0, stream>>>(ei, ew, dnrm, cursor, erec, E);
            k_cvt_w<<<(NFIELD * FEAT * FEAT + 255) / 256, 256, 0, stream>>>(Wg, Wr, Wh, wgT, wrT, whT);
            k_cvt_x<<<(cnt4 + 255) / 256, 256, 0, stream>>>(x + (size_t)f * n * FEAT, xb, cnt4);
            k_gather<<<gblocks, 256, 0, stream>>>(erec, dnrm, rowptr, xb, xab, n, 1);
            k_gemm_mfma<<<ggemm, 256, 0, stream>>>(xb, xab, wgT, wrT, whT, out, n, f, 1);
        }
    }
}